// Round 1
// baseline (68.837 us; speedup 1.0000x reference)
//
#include <hip/hip_runtime.h>

// out[b,i,j] = sum_d W[d] * x[b,i,d] * x[b,j,d] + b[0]
// (lin terms cancel under symmetrization; bilin is already symmetric)
// B=2, L=512, D=256, fp32 throughout.

constexpr int Lc   = 512;
constexpr int Dc   = 256;
constexpr int TILE = 32;   // output tile 32x32 per block
constexpr int KC   = 32;   // K-chunk staged in LDS

__global__ __launch_bounds__(256, 4)
void pairwise_head_kernel(const float* __restrict__ x,    // (B,L,D)
                          const float* __restrict__ W,    // (2D,1), first D = w1
                          const float* __restrict__ bvec, // (1,)
                          float* __restrict__ out)        // (B,L,L)
{
    __shared__ float As[TILE][TILE + 1];  // +1 pad: conflict-free column reads
    __shared__ float Bs[TILE][TILE + 1];

    const int t  = threadIdx.x;
    const int tx = t & 15;        // 16x16 threads, each 2x2 outputs
    const int ty = t >> 4;
    const int j0 = blockIdx.x * TILE;
    const int i0 = blockIdx.y * TILE;
    const int b  = blockIdx.z;

    const float* xb = x + (size_t)b * Lc * Dc;

    // staging: 32 rows x 32 K-floats = 256 float4 loads, one per thread
    const int lrow = t >> 3;            // 0..31
    const int lcol = (t & 7) << 2;      // 0,4,...,28

    const float* aptr = xb + (size_t)(i0 + lrow) * Dc + lcol;
    const float* bptr = xb + (size_t)(j0 + lrow) * Dc + lcol;
    const float* wptr = W + lcol;       // w1 = W[:D]

    float acc00 = 0.f, acc01 = 0.f, acc10 = 0.f, acc11 = 0.f;

    for (int kc = 0; kc < Dc; kc += KC) {
        const float4 av = *(const float4*)(aptr + kc);
        const float4 bv = *(const float4*)(bptr + kc);
        const float4 wv = *(const float4*)(wptr + kc);
        if (kc) __syncthreads();            // protect prior-iter LDS reads
        As[lrow][lcol + 0] = av.x * wv.x;   // fold w1 into A stage
        As[lrow][lcol + 1] = av.y * wv.y;
        As[lrow][lcol + 2] = av.z * wv.z;
        As[lrow][lcol + 3] = av.w * wv.w;
        Bs[lrow][lcol + 0] = bv.x;
        Bs[lrow][lcol + 1] = bv.y;
        Bs[lrow][lcol + 2] = bv.z;
        Bs[lrow][lcol + 3] = bv.w;
        __syncthreads();

#pragma unroll
        for (int k = 0; k < KC; k += 2) {   // float2 LDS reads (ds_read_b64)
            const float2 a0 = *(const float2*)&As[2 * ty    ][k];
            const float2 a1 = *(const float2*)&As[2 * ty + 1][k];
            const float2 b0 = *(const float2*)&Bs[2 * tx    ][k];
            const float2 b1 = *(const float2*)&Bs[2 * tx + 1][k];
            acc00 += a0.x * b0.x + a0.y * b0.y;
            acc01 += a0.x * b1.x + a0.y * b1.y;
            acc10 += a1.x * b0.x + a1.y * b0.y;
            acc11 += a1.x * b1.x + a1.y * b1.y;
        }
    }

    const float bb = bvec[0];
    float* orow = out + ((size_t)b * Lc + (i0 + 2 * ty)) * Lc + (j0 + 2 * tx);
    const float2 r0 = make_float2(acc00 + bb, acc01 + bb);
    const float2 r1 = make_float2(acc10 + bb, acc11 + bb);
    *(float2*)orow        = r0;
    *(float2*)(orow + Lc) = r1;
}

extern "C" void kernel_launch(void* const* d_in, const int* in_sizes, int n_in,
                              void* d_out, int out_size, void* d_ws, size_t ws_size,
                              hipStream_t stream) {
    const float* x    = (const float*)d_in[0];  // (2,512,256) f32
    const float* W    = (const float*)d_in[1];  // (512,1)     f32
    const float* bias = (const float*)d_in[2];  // (1,)        f32
    float* out        = (float*)d_out;          // (2,512,512,1) f32

    dim3 grid(Lc / TILE, Lc / TILE, 2);         // 16 x 16 x 2 = 512 blocks
    dim3 block(256);
    pairwise_head_kernel<<<grid, block, 0, stream>>>(x, W, bias, out);
}

// Round 2
// 65.847 us; speedup vs baseline: 1.0454x; 1.0454x over previous
//
#include <hip/hip_runtime.h>
#include <hip/hip_bf16.h>

// out[b,i,j] = sum_d W[d] * x[b,i,d] * x[b,j,d] + b[0]
// (antisymmetric lin terms cancel under symmetrization; bilin is symmetric)
// B=2, L=512, D=256. bf16 MFMA Gram matrix: B-operand = A-operand pattern
// (B = X^T), so any self-consistent k-slot fill is correct by permutation
// invariance; C/D layout is the HW-verified 16x16 mapping.

constexpr int Lc = 512;
constexpr int Dc = 256;

typedef __attribute__((ext_vector_type(8))) short short8;   // 8 bf16 (4 VGPRs)
typedef __attribute__((ext_vector_type(4))) float f32x4;    // 4 fp32 acc

__device__ __forceinline__ short f2bf(float f) {
    __hip_bfloat16 h = __float2bfloat16(f);
    return __builtin_bit_cast(short, h);
}

__global__ __launch_bounds__(64)
void pairwise_mfma_kernel(const float* __restrict__ x,    // (B,L,D) f32
                          const float* __restrict__ W,    // (2D,1)  f32, w1=W[:D]
                          const float* __restrict__ bvec, // (1,)
                          float* __restrict__ out)        // (B,L,L) f32
{
    const int lane = threadIdx.x;          // 0..63
    const int j0 = blockIdx.x * 16;
    const int i0 = blockIdx.y * 16;
    const int b  = blockIdx.z;

    const int lm = lane & 15;              // row within 16-tile
    const int kh = lane >> 4;              // 0..3 -> k-subchunk of 8

    const float* xa = x + (size_t)b * Lc * Dc + (size_t)(i0 + lm) * Dc + 8 * kh;
    const float* xb = x + (size_t)b * Lc * Dc + (size_t)(j0 + lm) * Dc + 8 * kh;
    const float* wp = W + 8 * kh;          // w1 chunk for this lane's k-slots

    f32x4 acc = {0.f, 0.f, 0.f, 0.f};

#pragma unroll
    for (int ks = 0; ks < Dc; ks += 32) {  // one mfma_16x16x32 per step
        const float4 a0 = *(const float4*)(xa + ks);
        const float4 a1 = *(const float4*)(xa + ks + 4);
        const float4 b0 = *(const float4*)(xb + ks);
        const float4 b1 = *(const float4*)(xb + ks + 4);
        const float4 w0 = *(const float4*)(wp + ks);
        const float4 w1 = *(const float4*)(wp + ks + 4);

        short8 af, bf;
        af[0] = f2bf(a0.x * w0.x);  af[1] = f2bf(a0.y * w0.y);
        af[2] = f2bf(a0.z * w0.z);  af[3] = f2bf(a0.w * w0.w);
        af[4] = f2bf(a1.x * w1.x);  af[5] = f2bf(a1.y * w1.y);
        af[6] = f2bf(a1.z * w1.z);  af[7] = f2bf(a1.w * w1.w);
        bf[0] = f2bf(b0.x);         bf[1] = f2bf(b0.y);
        bf[2] = f2bf(b0.z);         bf[3] = f2bf(b0.w);
        bf[4] = f2bf(b1.x);         bf[5] = f2bf(b1.y);
        bf[6] = f2bf(b1.z);         bf[7] = f2bf(b1.w);

        acc = __builtin_amdgcn_mfma_f32_16x16x32_bf16(af, bf, acc, 0, 0, 0);
    }

    // C/D layout (HW-verified): col = lane&15, row = 4*(lane>>4) + reg
    const float bb = bvec[0];
    float* op = out + ((size_t)b * Lc + (i0 + 4 * kh)) * Lc + (j0 + lm);
#pragma unroll
    for (int r = 0; r < 4; ++r)
        op[(size_t)r * Lc] = acc[r] + bb;
}

extern "C" void kernel_launch(void* const* d_in, const int* in_sizes, int n_in,
                              void* d_out, int out_size, void* d_ws, size_t ws_size,
                              hipStream_t stream) {
    const float* x    = (const float*)d_in[0];  // (2,512,256) f32
    const float* W    = (const float*)d_in[1];  // (512,1)     f32
    const float* bias = (const float*)d_in[2];  // (1,)        f32
    float* out        = (float*)d_out;          // (2,512,512,1) f32

    dim3 grid(Lc / 16, Lc / 16, 2);             // 32 x 32 x 2 = 2048 waves
    dim3 block(64);
    pairwise_mfma_kernel<<<grid, block, 0, stream>>>(x, W, bias, out);
}

// Round 3
// 61.331 us; speedup vs baseline: 1.1224x; 1.0736x over previous
//
#include <hip/hip_runtime.h>
#include <hip/hip_bf16.h>

// out[b,i,j] = sum_d W[d] * x[b,i,d] * x[b,j,d] + b[0]
// (antisymmetric lin terms cancel; bilin is symmetric)
// Pass 1: a' = bf16(w1*x), b' = bf16(x) into d_ws (conversion paid ONCE).
// Pass 2: pure-bf16 Gram GEMM, one wave per 32x32 tile, 2x2 mfma_16x16x32
// fragments (A/B use the identical self-consistent k-slot fill; correct by
// permutation invariance since B = X^T has A's load pattern).

constexpr int Lc = 512;
constexpr int Dc = 256;

typedef __attribute__((ext_vector_type(8))) short short8;  // 8 bf16
typedef __attribute__((ext_vector_type(4))) float f32x4;

__device__ __forceinline__ short f2bf(float f) {
    __hip_bfloat16 h = __float2bfloat16(f);
    return __builtin_bit_cast(short, h);
}

// 2*512*256 = 262144 elements per array; 8 per thread, 256 thr -> 128 blocks
__global__ __launch_bounds__(256)
void convert_kernel(const float* __restrict__ x, const float* __restrict__ W,
                    short* __restrict__ aws, short* __restrict__ bws)
{
    const int base = (blockIdx.x * 256 + threadIdx.x) * 8;
    const int d = base & (Dc - 1);          // rows are Dc-aligned, 8 | Dc

    const float4 x0 = *(const float4*)(x + base);
    const float4 x1 = *(const float4*)(x + base + 4);
    const float4 w0 = *(const float4*)(W + d);
    const float4 w1 = *(const float4*)(W + d + 4);

    short8 a, b;
    a[0] = f2bf(x0.x * w0.x); a[1] = f2bf(x0.y * w0.y);
    a[2] = f2bf(x0.z * w0.z); a[3] = f2bf(x0.w * w0.w);
    a[4] = f2bf(x1.x * w1.x); a[5] = f2bf(x1.y * w1.y);
    a[6] = f2bf(x1.z * w1.z); a[7] = f2bf(x1.w * w1.w);
    b[0] = f2bf(x0.x); b[1] = f2bf(x0.y); b[2] = f2bf(x0.z); b[3] = f2bf(x0.w);
    b[4] = f2bf(x1.x); b[5] = f2bf(x1.y); b[6] = f2bf(x1.z); b[7] = f2bf(x1.w);

    *(short8*)(aws + base) = a;
    *(short8*)(bws + base) = b;
}

__global__ __launch_bounds__(64)
void gram_mfma_kernel(const short* __restrict__ aws,  // (B,L,D) bf16, w-folded
                      const short* __restrict__ bws,  // (B,L,D) bf16
                      const float* __restrict__ bvec,
                      float* __restrict__ out)        // (B,L,L) f32
{
    const int lane = threadIdx.x;
    const int j0 = blockIdx.x * 32;
    const int i0 = blockIdx.y * 32;
    const int b  = blockIdx.z;

    const int lm = lane & 15;
    const int kh = lane >> 4;               // k-subchunk of 8 within 32

    const size_t xoff = (size_t)b * Lc * Dc;
    const short* ap0 = aws + xoff + (size_t)(i0 + lm)      * Dc + 8 * kh;
    const short* ap1 = aws + xoff + (size_t)(i0 + 16 + lm) * Dc + 8 * kh;
    const short* bp0 = bws + xoff + (size_t)(j0 + lm)      * Dc + 8 * kh;
    const short* bp1 = bws + xoff + (size_t)(j0 + 16 + lm) * Dc + 8 * kh;

    f32x4 acc00 = {0,0,0,0}, acc01 = {0,0,0,0};
    f32x4 acc10 = {0,0,0,0}, acc11 = {0,0,0,0};

#pragma unroll
    for (int ks = 0; ks < Dc; ks += 32) {
        const short8 a0 = *(const short8*)(ap0 + ks);
        const short8 a1 = *(const short8*)(ap1 + ks);
        const short8 b0 = *(const short8*)(bp0 + ks);
        const short8 b1 = *(const short8*)(bp1 + ks);
        acc00 = __builtin_amdgcn_mfma_f32_16x16x32_bf16(a0, b0, acc00, 0, 0, 0);
        acc01 = __builtin_amdgcn_mfma_f32_16x16x32_bf16(a0, b1, acc01, 0, 0, 0);
        acc10 = __builtin_amdgcn_mfma_f32_16x16x32_bf16(a1, b0, acc10, 0, 0, 0);
        acc11 = __builtin_amdgcn_mfma_f32_16x16x32_bf16(a1, b1, acc11, 0, 0, 0);
    }

    // C/D: col = lane&15, row = 4*(lane>>4) + reg  (per 16x16 quadrant)
    const float bb = bvec[0];
    const size_t obase = (size_t)b * Lc * Lc;
#pragma unroll
    for (int r = 0; r < 4; ++r) {
        const size_t row0 = i0 + 4 * kh + r;
        out[obase + row0 * Lc + (j0 + lm)]             = acc00[r] + bb;
        out[obase + row0 * Lc + (j0 + 16 + lm)]        = acc01[r] + bb;
        out[obase + (row0 + 16) * Lc + (j0 + lm)]      = acc10[r] + bb;
        out[obase + (row0 + 16) * Lc + (j0 + 16 + lm)] = acc11[r] + bb;
    }
}

extern "C" void kernel_launch(void* const* d_in, const int* in_sizes, int n_in,
                              void* d_out, int out_size, void* d_ws, size_t ws_size,
                              hipStream_t stream) {
    const float* x    = (const float*)d_in[0];  // (2,512,256) f32
    const float* W    = (const float*)d_in[1];  // (512,1)     f32
    const float* bias = (const float*)d_in[2];  // (1,)        f32
    float* out        = (float*)d_out;          // (2,512,512,1) f32

    short* aws = (short*)d_ws;                       // 262144 bf16 = 512 KB
    short* bws = (short*)d_ws + (size_t)2 * Lc * Dc; // next 512 KB

    convert_kernel<<<dim3(128), dim3(256), 0, stream>>>(x, W, aws, bws);
    gram_mfma_kernel<<<dim3(Lc / 32, Lc / 32, 2), dim3(64), 0, stream>>>(
        aws, bws, bias, out);
}